// Round 17
// baseline (176.765 us; speedup 1.0000x reference)
//
#include <hip/hip_runtime.h>
#include <hip/hip_fp16.h>

// GCN: 2x (h@W -> symmetric-norm neighbor aggregation +bias, relu) -> h@Wl+bl
// N=100000, E=1600000, D=H=64, C=16.
// Round 17: dispatch-plumbing consolidation on top of r16 (174.7us):
//  - k_bscan removed: each k_bfin block computes its own exclusive prefix of
//    gcursor (391 L2-hot ints, LDS reduce).
//  - k_final fused into layer-2 aggregate as SEPARATE PLAIN FUNCTION
//    k_aggfin (exact r14 loop body; epilogue-only change; no template
//    co-instantiation with k_aggregate, no prefetch -- r15's regression).
//  - k_aggregate (layer 1) byte-identical to r16: canary for codegen drift.
// Aggregate: 8 edges/VMEM fp16 rows. Transforms: fp16 MFMA 16x16x32.
// CSR: partition->fixed-CAP regions+spill, per-block-prefix bfin scatter.

#define WS_ALIGN 256
#define BSHIFT 8            // 256 nodes per bucket
#define MAXBUCK 512         // n=100000 -> nbuck=391
#define CAP 6144            // bucket region capacity (mean 4092, +32 sigma)

typedef _Float16 half8 __attribute__((ext_vector_type(8)));
typedef float floatx4 __attribute__((ext_vector_type(4)));

// ---------------- CSR build ----------------

// partition edges into fixed-CAP bucket regions (pair packed src<<8|dst&255);
// gcursor accumulates true totals; overflow -> spill list (empty in practice).
__global__ void k_partition(const int* __restrict__ src, const int* __restrict__ dst,
                            int* __restrict__ gcursor, int* __restrict__ spillcnt,
                            int* __restrict__ bpairs, int2* __restrict__ spill,
                            int e, int nbuck) {
    __shared__ int hist[MAXBUCK];
    __shared__ int lbase[MAXBUCK];
    const int CH = 4096;
    int base = blockIdx.x * CH;
    int end = base + CH; if (end > e) end = e;
    for (int t = threadIdx.x; t < nbuck; t += blockDim.x) hist[t] = 0;
    __syncthreads();
    for (int i = base + threadIdx.x; i < end; i += blockDim.x)
        atomicAdd(&hist[dst[i] >> BSHIFT], 1);
    __syncthreads();
    for (int t = threadIdx.x; t < nbuck; t += blockDim.x) {
        int c = hist[t];
        lbase[t] = (c > 0) ? atomicAdd(&gcursor[t], c) : 0;
        hist[t] = 0;                              // reuse as local cursor
    }
    __syncthreads();
    for (int i = base + threadIdx.x; i < end; i += blockDim.x) {
        int s = src[i], d = dst[i];
        int b = d >> BSHIFT;
        int pos = lbase[b] + atomicAdd(&hist[b], 1);
        int packed = (s << BSHIFT) | (d & ((1 << BSHIFT) - 1));
        if (pos < CAP) bpairs[b * CAP + pos] = packed;
        else { int si = atomicAdd(spillcnt, 1); spill[si] = make_int2(b, packed); }
    }
}

// per-bucket finalize: in-block exclusive prefix of gcursor -> lo, node
// counts (LDS, incl. spill), 256-entry scan, ocnt/inv write, exact scatter.
__global__ void k_bfin(const int* __restrict__ bpairs, const int* __restrict__ gcursor,
                       const int* __restrict__ spillcnt, const int2* __restrict__ spill,
                       int2* __restrict__ ocnt, float* __restrict__ inv,
                       int* __restrict__ ssrc, int n, int nbuck) {
    __shared__ int lcnt[256];
    __shared__ int tmp[256];
    __shared__ int loff[256];
    __shared__ int lcur[256];
    __shared__ int s_lo;
    const int b = blockIdx.x;
    const int t = threadIdx.x;                 // blockDim = 256
    // exclusive prefix: lo = sum of gcursor[i] for i < b
    {
        int partial = 0;
        for (int i = t; i < b; i += 256) partial += gcursor[i];
        tmp[t] = partial;
        __syncthreads();
        #pragma unroll
        for (int d = 128; d > 0; d >>= 1) {
            if (t < d) tmp[t] += tmp[t + d];
            __syncthreads();
        }
        if (t == 0) s_lo = tmp[0];
        __syncthreads();
    }
    const int lo = s_lo;
    const int tot = gcursor[b];
    const int reg = (tot < CAP) ? tot : CAP;
    const int rb = b * CAP;
    const int spn = *spillcnt;
    lcnt[t] = 0; lcur[t] = 0;
    __syncthreads();
    for (int i = t; i < reg; i += 256)
        atomicAdd(&lcnt[bpairs[rb + i] & 255], 1);
    for (int i = t; i < spn; i += 256) {
        int2 sp = spill[i];
        if (sp.x == b) atomicAdd(&lcnt[sp.y & 255], 1);
    }
    __syncthreads();
    int v = lcnt[t];
    tmp[t] = v;
    __syncthreads();
    int x = v;
    #pragma unroll
    for (int d = 1; d < 256; d <<= 1) {
        int y = (t >= d) ? tmp[t - d] : 0;
        __syncthreads();
        x += y;
        tmp[t] = x;
        __syncthreads();
    }
    loff[t] = x - v;
    int node = (b << BSHIFT) + t;
    if (node < n) {
        ocnt[node] = make_int2(lo + (x - v), v);
        inv[node] = rsqrtf((float)v + 1.0f);
    }
    __syncthreads();
    for (int i = t; i < reg; i += 256) {
        int p = bpairs[rb + i];
        int l = p & 255;
        int pos = lo + loff[l] + atomicAdd(&lcur[l], 1);
        ssrc[pos] = p >> BSHIFT;
    }
    for (int i = t; i < spn; i += 256) {
        int2 sp = spill[i];
        if (sp.x == b) {
            int l = sp.y & 255;
            int pos = lo + loff[l] + atomicAdd(&lcur[l], 1);
            ssrc[pos] = sp.y >> BSHIFT;
        }
    }
}

// ---------------- MFMA transform: t'[row][:] = fp16((in[row][:] @ W) * inv[row]) --------

__device__ __forceinline__ void loadA(const float* in, size_t base, half8& a) {
    float4 lo = *reinterpret_cast<const float4*>(in + base);
    float4 hi = *reinterpret_cast<const float4*>(in + base + 16);
    a[0] = (_Float16)lo.x; a[1] = (_Float16)lo.y; a[2] = (_Float16)lo.z; a[3] = (_Float16)lo.w;
    a[4] = (_Float16)hi.x; a[5] = (_Float16)hi.y; a[6] = (_Float16)hi.z; a[7] = (_Float16)hi.w;
}
__device__ __forceinline__ void loadA(const __half* in, size_t base, half8& a) {
    const _Float16* p = reinterpret_cast<const _Float16*>(in + base);
    #pragma unroll
    for (int j = 0; j < 4; ++j) { a[j] = p[j]; a[4 + j] = p[16 + j]; }
}

template <typename Tin>
__global__ void __launch_bounds__(256, 4)
k_transform(const Tin* __restrict__ in, const float* __restrict__ W,
            const float* __restrict__ inv, __half* __restrict__ out, int n) {
    const int lane = threadIdx.x & 63;
    const int m = lane & 15, g = lane >> 4;
    const int wid = blockIdx.x * 4 + (threadIdx.x >> 6);
    const int nw = gridDim.x * 4;

    half8 bf[4][2];
    #pragma unroll
    for (int t = 0; t < 4; ++t)
        #pragma unroll
        for (int s = 0; s < 2; ++s) {
            #pragma unroll
            for (int j = 0; j < 4; ++j) {
                bf[t][s][j]     = (_Float16)W[(32 * s + 4 * g + j) * 64 + 16 * t + m];
                bf[t][s][4 + j] = (_Float16)W[(32 * s + 16 + 4 * g + j) * 64 + 16 * t + m];
            }
        }

    const int ntile = (n + 15) >> 4;
    for (int tile = wid; tile < ntile; tile += nw) {
        const int rbase = tile << 4;
        int arow = rbase + m; if (arow >= n) arow = n - 1;
        half8 a[2];
        loadA(in, (size_t)arow * 64 + 0  + 4 * g, a[0]);
        loadA(in, (size_t)arow * 64 + 32 + 4 * g, a[1]);

        floatx4 acc[4] = {{0.f,0.f,0.f,0.f},{0.f,0.f,0.f,0.f},{0.f,0.f,0.f,0.f},{0.f,0.f,0.f,0.f}};
        #pragma unroll
        for (int s = 0; s < 2; ++s)
            #pragma unroll
            for (int t = 0; t < 4; ++t)
                acc[t] = __builtin_amdgcn_mfma_f32_16x16x32_f16(a[s], bf[t][s], acc[t], 0, 0, 0);

        #pragma unroll
        for (int reg = 0; reg < 4; ++reg) {
            int row = rbase + 4 * g + reg;
            if (row < n) {
                float iv = inv[row];
                #pragma unroll
                for (int t = 0; t < 4; ++t)
                    out[(size_t)row * 64 + 16 * t + m] = __float2half(acc[t][reg] * iv);
            }
        }
    }
}

// ---------------- aggregation (layer 1): h = fp16(relu((sum+self)*inv + b)) --------
// EXACT round-14/16 kernel (canary -- do not modify).

__global__ void __launch_bounds__(256, 8)
k_aggregate(const __half* __restrict__ t, const int* __restrict__ ssrc,
            const int2* __restrict__ ocnt, const float* __restrict__ inv,
            const float* __restrict__ b, __half* __restrict__ out,
            int n, int do_relu) {
    const int lane = threadIdx.x & 63;
    const int g = lane >> 3;        // edge slot 0..7
    const int f = lane & 7;         // feature octet 0..7
    const int wid = blockIdx.x * (blockDim.x >> 6) + (threadIdx.x >> 6);
    const int nw = gridDim.x * (blockDim.x >> 6);
    float b8[8];
    #pragma unroll
    for (int q = 0; q < 8; ++q) b8[q] = b[f * 8 + q];

    for (int node = wid; node < n; node += nw) {
        const int2 oc = ocnt[node];
        const int start = oc.x, cnt = oc.y;
        const int tot = cnt + 1;                    // + self-loop
        float acc[8] = {0.f,0.f,0.f,0.f,0.f,0.f,0.f,0.f};
        for (int be = 0; be < tot; be += 64) {
            int lim = tot - be; if (lim > 64) lim = 64;
            int myidx = (be + lane < cnt) ? ssrc[start + be + lane] : node;
            for (int j = 0; j < lim; j += 8) {
                int epos = j + g;
                int sidx = __shfl(myidx, epos);             // bpermute
                float wt = (epos < lim) ? 1.f : 0.f;
                float4 raw = *reinterpret_cast<const float4*>(t + (size_t)sidx * 64 + f * 8);
                const __half2* hp = reinterpret_cast<const __half2*>(&raw);
                #pragma unroll
                for (int q = 0; q < 4; ++q) {
                    float2 fv = __half22float2(hp[q]);
                    acc[2 * q]     = fmaf(fv.x, wt, acc[2 * q]);
                    acc[2 * q + 1] = fmaf(fv.y, wt, acc[2 * q + 1]);
                }
            }
        }
        #pragma unroll
        for (int off = 8; off < 64; off <<= 1)
            #pragma unroll
            for (int q = 0; q < 8; ++q)
                acc[q] += __shfl_xor(acc[q], off);
        if (g == 0) {
            const float iv = inv[node];
            __half hres[8];
            #pragma unroll
            for (int q = 0; q < 8; ++q) {
                float r = fmaf(acc[q], iv, b8[q]);
                if (do_relu) r = fmaxf(r, 0.f);
                hres[q] = __float2half(r);
            }
            *reinterpret_cast<float4*>(out + (size_t)node * 64 + f * 8) =
                *reinterpret_cast<const float4*>(hres);
        }
    }
}

// ---------------- aggregation (layer 2) + fused final projection ----------------
// Same loop body as k_aggregate; epilogue: h (in-register, all lanes hold the
// full row after butterfly) @ Wl + bl -> out[n][16] fp32. Lane (g,f) computes
// cols 2g,2g+1 partials over its 8 h vals; shfl_xor(1/2/4) reduces over f.

__global__ void __launch_bounds__(256, 8)
k_aggfin(const __half* __restrict__ t, const int* __restrict__ ssrc,
         const int2* __restrict__ ocnt, const float* __restrict__ inv,
         const float* __restrict__ b, const float* __restrict__ Wl,
         const float* __restrict__ bl, float* __restrict__ out, int n) {
    const int lane = threadIdx.x & 63;
    const int g = lane >> 3;        // edge slot / output col pair
    const int f = lane & 7;         // feature octet
    const int wid = blockIdx.x * (blockDim.x >> 6) + (threadIdx.x >> 6);
    const int nw = gridDim.x * (blockDim.x >> 6);
    float b8[8], wl0[8], wl1[8];
    #pragma unroll
    for (int q = 0; q < 8; ++q) {
        b8[q] = b[f * 8 + q];
        wl0[q] = Wl[(f * 8 + q) * 16 + 2 * g];
        wl1[q] = Wl[(f * 8 + q) * 16 + 2 * g + 1];
    }
    const float bl0 = bl[2 * g], bl1 = bl[2 * g + 1];

    for (int node = wid; node < n; node += nw) {
        const int2 oc = ocnt[node];
        const int start = oc.x, cnt = oc.y;
        const int tot = cnt + 1;                    // + self-loop
        float acc[8] = {0.f,0.f,0.f,0.f,0.f,0.f,0.f,0.f};
        for (int be = 0; be < tot; be += 64) {
            int lim = tot - be; if (lim > 64) lim = 64;
            int myidx = (be + lane < cnt) ? ssrc[start + be + lane] : node;
            for (int j = 0; j < lim; j += 8) {
                int epos = j + g;
                int sidx = __shfl(myidx, epos);             // bpermute
                float wt = (epos < lim) ? 1.f : 0.f;
                float4 raw = *reinterpret_cast<const float4*>(t + (size_t)sidx * 64 + f * 8);
                const __half2* hp = reinterpret_cast<const __half2*>(&raw);
                #pragma unroll
                for (int q = 0; q < 4; ++q) {
                    float2 fv = __half22float2(hp[q]);
                    acc[2 * q]     = fmaf(fv.x, wt, acc[2 * q]);
                    acc[2 * q + 1] = fmaf(fv.y, wt, acc[2 * q + 1]);
                }
            }
        }
        #pragma unroll
        for (int off = 8; off < 64; off <<= 1)
            #pragma unroll
            for (int q = 0; q < 8; ++q)
                acc[q] += __shfl_xor(acc[q], off);
        const float iv = inv[node];
        float p0 = 0.f, p1 = 0.f;
        #pragma unroll
        for (int q = 0; q < 8; ++q) {
            float h = fmaxf(fmaf(acc[q], iv, b8[q]), 0.f);   // relu(h2)
            p0 = fmaf(h, wl0[q], p0);
            p1 = fmaf(h, wl1[q], p1);
        }
        p0 += __shfl_xor(p0, 1); p0 += __shfl_xor(p0, 2); p0 += __shfl_xor(p0, 4);
        p1 += __shfl_xor(p1, 1); p1 += __shfl_xor(p1, 2); p1 += __shfl_xor(p1, 4);
        if (f == 0) {
            float2 o = make_float2(p0 + bl0, p1 + bl1);
            *reinterpret_cast<float2*>(out + (size_t)node * 16 + 2 * g) = o;
        }
    }
}

// ---------------- host ----------------

extern "C" void kernel_launch(void* const* d_in, const int* in_sizes, int n_in,
                              void* d_out, int out_size, void* d_ws, size_t ws_size,
                              hipStream_t stream) {
    const float* x  = (const float*)d_in[0];
    const int*   ei = (const int*)d_in[1];
    const float* W1 = (const float*)d_in[2];
    const float* b1 = (const float*)d_in[3];
    const float* W2 = (const float*)d_in[4];
    const float* b2 = (const float*)d_in[5];
    const float* Wl = (const float*)d_in[6];
    const float* bl = (const float*)d_in[7];
    float* out = (float*)d_out;

    const int n = in_sizes[0] / 64;
    const int e = in_sizes[1] / 2;
    const int* src = ei;
    const int* dst = ei + e;
    const int nbuck = (n + (1 << BSHIFT) - 1) >> BSHIFT;   // 391 for n=100000
    const int nchunk = (e + 4095) / 4096;

    char* ws = (char*)d_ws;
    size_t off = 0;
    auto alloc = [&](size_t bytes) -> void* {
        void* p = ws + off;
        off += (bytes + (WS_ALIGN - 1)) & ~((size_t)WS_ALIGN - 1);
        return p;
    };
    int*    gcursor = (int*)alloc((size_t)(MAXBUCK + 1) * 4);  // +1 = spillcnt
    int2*   ocnt    = (int2*)alloc((size_t)n * 8);
    float*  inv     = (float*)alloc((size_t)n * 4);
    int*    ssrc    = (int*)alloc((size_t)e * 4);
    __half* bufA    = (__half*)alloc((size_t)n * 64 * 2);   // t' (fp16)
    __half* bufB    = (__half*)alloc((size_t)n * 64 * 2);   // h1 (fp16)
    int*    bpairs  = (int*)bufA;   // alias: nbuck*CAP*4 = 9.6MB <= 12.8MB
    int2*   spill   = (int2*)bufB;  // alias: used only during CSR build
    int*    spillcnt = gcursor + MAXBUCK;

    hipMemsetAsync(gcursor, 0, (size_t)(MAXBUCK + 1) * 4, stream);

    k_partition<<<nchunk, 256, 0, stream>>>(src, dst, gcursor, spillcnt, bpairs, spill, e, nbuck);
    k_bfin<<<nbuck, 256, 0, stream>>>(bpairs, gcursor, spillcnt, spill, ocnt, inv, ssrc, n, nbuck);

    const int ntile = (n + 15) / 16;
    const int tgrid = (ntile + 3) / 4;        // 1 tile per wave, 4 waves/block
    // layer 1: t' = fp16((x@W1)*inv) ; h1 = fp16(relu((sum+self)*inv + b1))
    k_transform<float><<<tgrid, 256, 0, stream>>>(x, W1, inv, bufA, n);
    k_aggregate<<<2048, 256, 0, stream>>>(bufA, ssrc, ocnt, inv, b1, bufB, n, 1);
    // layer 2 + fused readout
    k_transform<__half><<<tgrid, 256, 0, stream>>>(bufB, W2, inv, bufA, n);
    k_aggfin<<<2048, 256, 0, stream>>>(bufA, ssrc, ocnt, inv, b2, Wl, bl, out, n);
}

// Round 18
// 172.427 us; speedup vs baseline: 1.0252x; 1.0252x over previous
//
#include <hip/hip_runtime.h>
#include <hip/hip_fp16.h>

// GCN: 2x (h@W -> symmetric-norm neighbor aggregation +bias, relu) -> h@Wl+bl
// N=100000, E=1600000, D=H=64, C=16.
// Round 18: compose verified-best parts. r16 kernel set EXACTLY (aggregate
// canary 46us/86MB untouched; separate k_final -- BOTH fusion attempts r15/
// r17 inflated gather FETCH ~40%, reproducibly: do not fuse into the gather
// kernel) + r17's verified bscan-free CSR build (k_bfin computes its own
// exclusive prefix of gcursor; one fewer dispatch).
// Aggregate: 8 edges/VMEM fp16 rows (r14). Transforms: fp16 MFMA 16x16x32
// (r13). CSR: partition -> fixed-CAP bucket regions + spill (r15).

#define WS_ALIGN 256
#define BSHIFT 8            // 256 nodes per bucket
#define MAXBUCK 512         // n=100000 -> nbuck=391
#define CAP 6144            // bucket region capacity (mean 4092, +32 sigma)

typedef _Float16 half8 __attribute__((ext_vector_type(8)));
typedef float floatx4 __attribute__((ext_vector_type(4)));

// ---------------- CSR build ----------------

// partition edges into fixed-CAP bucket regions (pair packed src<<8|dst&255);
// gcursor accumulates true totals; overflow -> spill list (empty in practice).
__global__ void k_partition(const int* __restrict__ src, const int* __restrict__ dst,
                            int* __restrict__ gcursor, int* __restrict__ spillcnt,
                            int* __restrict__ bpairs, int2* __restrict__ spill,
                            int e, int nbuck) {
    __shared__ int hist[MAXBUCK];
    __shared__ int lbase[MAXBUCK];
    const int CH = 4096;
    int base = blockIdx.x * CH;
    int end = base + CH; if (end > e) end = e;
    for (int t = threadIdx.x; t < nbuck; t += blockDim.x) hist[t] = 0;
    __syncthreads();
    for (int i = base + threadIdx.x; i < end; i += blockDim.x)
        atomicAdd(&hist[dst[i] >> BSHIFT], 1);
    __syncthreads();
    for (int t = threadIdx.x; t < nbuck; t += blockDim.x) {
        int c = hist[t];
        lbase[t] = (c > 0) ? atomicAdd(&gcursor[t], c) : 0;
        hist[t] = 0;                              // reuse as local cursor
    }
    __syncthreads();
    for (int i = base + threadIdx.x; i < end; i += blockDim.x) {
        int s = src[i], d = dst[i];
        int b = d >> BSHIFT;
        int pos = lbase[b] + atomicAdd(&hist[b], 1);
        int packed = (s << BSHIFT) | (d & ((1 << BSHIFT) - 1));
        if (pos < CAP) bpairs[b * CAP + pos] = packed;
        else { int si = atomicAdd(spillcnt, 1); spill[si] = make_int2(b, packed); }
    }
}

// per-bucket finalize: in-block exclusive prefix of gcursor -> lo, node
// counts (LDS, incl. spill), 256-entry scan, ocnt/inv write, exact scatter.
__global__ void k_bfin(const int* __restrict__ bpairs, const int* __restrict__ gcursor,
                       const int* __restrict__ spillcnt, const int2* __restrict__ spill,
                       int2* __restrict__ ocnt, float* __restrict__ inv,
                       int* __restrict__ ssrc, int n, int nbuck) {
    __shared__ int lcnt[256];
    __shared__ int tmp[256];
    __shared__ int loff[256];
    __shared__ int lcur[256];
    __shared__ int s_lo;
    const int b = blockIdx.x;
    const int t = threadIdx.x;                 // blockDim = 256
    // exclusive prefix: lo = sum of gcursor[i] for i < b
    {
        int partial = 0;
        for (int i = t; i < b; i += 256) partial += gcursor[i];
        tmp[t] = partial;
        __syncthreads();
        #pragma unroll
        for (int d = 128; d > 0; d >>= 1) {
            if (t < d) tmp[t] += tmp[t + d];
            __syncthreads();
        }
        if (t == 0) s_lo = tmp[0];
        __syncthreads();
    }
    const int lo = s_lo;
    const int tot = gcursor[b];
    const int reg = (tot < CAP) ? tot : CAP;
    const int rb = b * CAP;
    const int spn = *spillcnt;
    lcnt[t] = 0; lcur[t] = 0;
    __syncthreads();
    for (int i = t; i < reg; i += 256)
        atomicAdd(&lcnt[bpairs[rb + i] & 255], 1);
    for (int i = t; i < spn; i += 256) {
        int2 sp = spill[i];
        if (sp.x == b) atomicAdd(&lcnt[sp.y & 255], 1);
    }
    __syncthreads();
    int v = lcnt[t];
    tmp[t] = v;
    __syncthreads();
    int x = v;
    #pragma unroll
    for (int d = 1; d < 256; d <<= 1) {
        int y = (t >= d) ? tmp[t - d] : 0;
        __syncthreads();
        x += y;
        tmp[t] = x;
        __syncthreads();
    }
    loff[t] = x - v;
    int node = (b << BSHIFT) + t;
    if (node < n) {
        ocnt[node] = make_int2(lo + (x - v), v);
        inv[node] = rsqrtf((float)v + 1.0f);
    }
    __syncthreads();
    for (int i = t; i < reg; i += 256) {
        int p = bpairs[rb + i];
        int l = p & 255;
        int pos = lo + loff[l] + atomicAdd(&lcur[l], 1);
        ssrc[pos] = p >> BSHIFT;
    }
    for (int i = t; i < spn; i += 256) {
        int2 sp = spill[i];
        if (sp.x == b) {
            int l = sp.y & 255;
            int pos = lo + loff[l] + atomicAdd(&lcur[l], 1);
            ssrc[pos] = sp.y >> BSHIFT;
        }
    }
}

// ---------------- MFMA transform: t'[row][:] = fp16((in[row][:] @ W) * inv[row]) --------

__device__ __forceinline__ void loadA(const float* in, size_t base, half8& a) {
    float4 lo = *reinterpret_cast<const float4*>(in + base);
    float4 hi = *reinterpret_cast<const float4*>(in + base + 16);
    a[0] = (_Float16)lo.x; a[1] = (_Float16)lo.y; a[2] = (_Float16)lo.z; a[3] = (_Float16)lo.w;
    a[4] = (_Float16)hi.x; a[5] = (_Float16)hi.y; a[6] = (_Float16)hi.z; a[7] = (_Float16)hi.w;
}
__device__ __forceinline__ void loadA(const __half* in, size_t base, half8& a) {
    const _Float16* p = reinterpret_cast<const _Float16*>(in + base);
    #pragma unroll
    for (int j = 0; j < 4; ++j) { a[j] = p[j]; a[4 + j] = p[16 + j]; }
}

template <typename Tin>
__global__ void __launch_bounds__(256, 4)
k_transform(const Tin* __restrict__ in, const float* __restrict__ W,
            const float* __restrict__ inv, __half* __restrict__ out, int n) {
    const int lane = threadIdx.x & 63;
    const int m = lane & 15, g = lane >> 4;
    const int wid = blockIdx.x * 4 + (threadIdx.x >> 6);
    const int nw = gridDim.x * 4;

    half8 bf[4][2];
    #pragma unroll
    for (int t = 0; t < 4; ++t)
        #pragma unroll
        for (int s = 0; s < 2; ++s) {
            #pragma unroll
            for (int j = 0; j < 4; ++j) {
                bf[t][s][j]     = (_Float16)W[(32 * s + 4 * g + j) * 64 + 16 * t + m];
                bf[t][s][4 + j] = (_Float16)W[(32 * s + 16 + 4 * g + j) * 64 + 16 * t + m];
            }
        }

    const int ntile = (n + 15) >> 4;
    for (int tile = wid; tile < ntile; tile += nw) {
        const int rbase = tile << 4;
        int arow = rbase + m; if (arow >= n) arow = n - 1;
        half8 a[2];
        loadA(in, (size_t)arow * 64 + 0  + 4 * g, a[0]);
        loadA(in, (size_t)arow * 64 + 32 + 4 * g, a[1]);

        floatx4 acc[4] = {{0.f,0.f,0.f,0.f},{0.f,0.f,0.f,0.f},{0.f,0.f,0.f,0.f},{0.f,0.f,0.f,0.f}};
        #pragma unroll
        for (int s = 0; s < 2; ++s)
            #pragma unroll
            for (int t = 0; t < 4; ++t)
                acc[t] = __builtin_amdgcn_mfma_f32_16x16x32_f16(a[s], bf[t][s], acc[t], 0, 0, 0);

        #pragma unroll
        for (int reg = 0; reg < 4; ++reg) {
            int row = rbase + 4 * g + reg;
            if (row < n) {
                float iv = inv[row];
                #pragma unroll
                for (int t = 0; t < 4; ++t)
                    out[(size_t)row * 64 + 16 * t + m] = __float2half(acc[t][reg] * iv);
            }
        }
    }
}

// ---------------- aggregation: out[d] = fp16((sum_e t'[src] + t'[d]) * inv[d] + b) --------
// EXACT round-14/16 kernel (canary -- do not modify).

__global__ void __launch_bounds__(256, 8)
k_aggregate(const __half* __restrict__ t, const int* __restrict__ ssrc,
            const int2* __restrict__ ocnt, const float* __restrict__ inv,
            const float* __restrict__ b, __half* __restrict__ out,
            int n, int do_relu) {
    const int lane = threadIdx.x & 63;
    const int g = lane >> 3;        // edge slot 0..7
    const int f = lane & 7;         // feature octet 0..7
    const int wid = blockIdx.x * (blockDim.x >> 6) + (threadIdx.x >> 6);
    const int nw = gridDim.x * (blockDim.x >> 6);
    float b8[8];
    #pragma unroll
    for (int q = 0; q < 8; ++q) b8[q] = b[f * 8 + q];

    for (int node = wid; node < n; node += nw) {
        const int2 oc = ocnt[node];
        const int start = oc.x, cnt = oc.y;
        const int tot = cnt + 1;                    // + self-loop
        float acc[8] = {0.f,0.f,0.f,0.f,0.f,0.f,0.f,0.f};
        for (int be = 0; be < tot; be += 64) {
            int lim = tot - be; if (lim > 64) lim = 64;
            int myidx = (be + lane < cnt) ? ssrc[start + be + lane] : node;
            for (int j = 0; j < lim; j += 8) {
                int epos = j + g;
                int sidx = __shfl(myidx, epos);             // bpermute
                float wt = (epos < lim) ? 1.f : 0.f;
                float4 raw = *reinterpret_cast<const float4*>(t + (size_t)sidx * 64 + f * 8);
                const __half2* hp = reinterpret_cast<const __half2*>(&raw);
                #pragma unroll
                for (int q = 0; q < 4; ++q) {
                    float2 fv = __half22float2(hp[q]);
                    acc[2 * q]     = fmaf(fv.x, wt, acc[2 * q]);
                    acc[2 * q + 1] = fmaf(fv.y, wt, acc[2 * q + 1]);
                }
            }
        }
        #pragma unroll
        for (int off = 8; off < 64; off <<= 1)
            #pragma unroll
            for (int q = 0; q < 8; ++q)
                acc[q] += __shfl_xor(acc[q], off);
        if (g == 0) {
            const float iv = inv[node];
            __half hres[8];
            #pragma unroll
            for (int q = 0; q < 8; ++q) {
                float r = fmaf(acc[q], iv, b8[q]);
                if (do_relu) r = fmaxf(r, 0.f);
                hres[q] = __float2half(r);
            }
            *reinterpret_cast<float4*>(out + (size_t)node * 64 + f * 8) =
                *reinterpret_cast<const float4*>(hres);
        }
    }
}

// ---------------- final projection: out[n][16] = h[n][64] @ Wl[64][16] + bl ----------------

__global__ void k_final(const __half* __restrict__ h, const float* __restrict__ Wl,
                        const float* __restrict__ bl, float* __restrict__ out, int n) {
    __shared__ float Ws[64 * 16];
    for (int i = threadIdx.x; i < 64 * 16; i += blockDim.x) Ws[i] = Wl[i];
    __syncthreads();
    const int lane = threadIdx.x & 63;
    const int r = lane >> 4, c = lane & 15;
    const int wid = blockIdx.x * (blockDim.x >> 6) + (threadIdx.x >> 6);
    const int nw = gridDim.x * (blockDim.x >> 6);
    const float blc = bl[c];
    for (int base = wid * 4; base < n; base += nw * 4) {
        int row = base + r;
        if (row < n) {
            float acc = blc;
            const __half* hrow = h + (size_t)row * 64;
            #pragma unroll
            for (int kk = 0; kk < 8; ++kk) {
                float4 raw = *reinterpret_cast<const float4*>(hrow + kk * 8);
                const __half2* hp = reinterpret_cast<const __half2*>(&raw);
                #pragma unroll
                for (int j = 0; j < 4; ++j) {
                    float2 fv = __half22float2(hp[j]);
                    acc = fmaf(fv.x, Ws[(kk * 8 + 2 * j + 0) * 16 + c],
                          fmaf(fv.y, Ws[(kk * 8 + 2 * j + 1) * 16 + c], acc));
                }
            }
            out[(size_t)row * 16 + c] = acc;
        }
    }
}

// ---------------- host ----------------

extern "C" void kernel_launch(void* const* d_in, const int* in_sizes, int n_in,
                              void* d_out, int out_size, void* d_ws, size_t ws_size,
                              hipStream_t stream) {
    const float* x  = (const float*)d_in[0];
    const int*   ei = (const int*)d_in[1];
    const float* W1 = (const float*)d_in[2];
    const float* b1 = (const float*)d_in[3];
    const float* W2 = (const float*)d_in[4];
    const float* b2 = (const float*)d_in[5];
    const float* Wl = (const float*)d_in[6];
    const float* bl = (const float*)d_in[7];
    float* out = (float*)d_out;

    const int n = in_sizes[0] / 64;
    const int e = in_sizes[1] / 2;
    const int* src = ei;
    const int* dst = ei + e;
    const int nbuck = (n + (1 << BSHIFT) - 1) >> BSHIFT;   // 391 for n=100000
    const int nchunk = (e + 4095) / 4096;

    char* ws = (char*)d_ws;
    size_t off = 0;
    auto alloc = [&](size_t bytes) -> void* {
        void* p = ws + off;
        off += (bytes + (WS_ALIGN - 1)) & ~((size_t)WS_ALIGN - 1);
        return p;
    };
    int*    gcursor = (int*)alloc((size_t)(MAXBUCK + 1) * 4);  // +1 = spillcnt
    int2*   ocnt    = (int2*)alloc((size_t)n * 8);
    float*  inv     = (float*)alloc((size_t)n * 4);
    int*    ssrc    = (int*)alloc((size_t)e * 4);
    __half* bufA    = (__half*)alloc((size_t)n * 64 * 2);   // t' (fp16)
    __half* bufB    = (__half*)alloc((size_t)n * 64 * 2);   // h  (fp16)
    int*    bpairs  = (int*)bufA;   // alias: nbuck*CAP*4 = 9.6MB <= 12.8MB
    int2*   spill   = (int2*)bufB;  // alias: used only during CSR build
    int*    spillcnt = gcursor + MAXBUCK;

    hipMemsetAsync(gcursor, 0, (size_t)(MAXBUCK + 1) * 4, stream);

    k_partition<<<nchunk, 256, 0, stream>>>(src, dst, gcursor, spillcnt, bpairs, spill, e, nbuck);
    k_bfin<<<nbuck, 256, 0, stream>>>(bpairs, gcursor, spillcnt, spill, ocnt, inv, ssrc, n, nbuck);

    const int ntile = (n + 15) / 16;
    const int tgrid = (ntile + 3) / 4;        // 1 tile per wave, 4 waves/block
    // layer 1: t' = fp16((x@W1)*inv) ; h1 = fp16(relu((sum+self)*inv + b1))
    k_transform<float><<<tgrid, 256, 0, stream>>>(x, W1, inv, bufA, n);
    k_aggregate<<<2048, 256, 0, stream>>>(bufA, ssrc, ocnt, inv, b1, bufB, n, 1);
    // layer 2
    k_transform<__half><<<tgrid, 256, 0, stream>>>(bufB, W2, inv, bufA, n);
    k_aggregate<<<2048, 256, 0, stream>>>(bufA, ssrc, ocnt, inv, b2, bufB, n, 1);
    // readout
    k_final<<<2048, 256, 0, stream>>>(bufB, Wl, bl, out, n);
}